// Round 7
// baseline (204.914 us; speedup 1.0000x reference)
//
#include <hip/hip_runtime.h>
#include <math.h>

#define B_   128
#define T_   50
#define MI_  32
#define E_   128
#define EW_  16
#define D_   144
#define G_   432        // 3*D
#define N_   (B_*T_)    // 6400

// ---------------------------------------------------------------------------
// DPP butterfly add across 8 lanes (shared).
// ---------------------------------------------------------------------------
template<int CTRL>
__device__ __forceinline__ float dpp_xor_add(float x) {
    int y = __builtin_amdgcn_mov_dpp(__float_as_int(x), CTRL, 0xF, 0xF, true);
    return x + __int_as_float(y);
}
#define DPP_RED3(v) \
    v = dpp_xor_add<0xB1>(v); v = dpp_xor_add<0x4E>(v); v = dpp_xor_add<0x141>(v);

// ---------------------------------------------------------------------------
// K12: fused embed + gi matvec.  Persistent 256 blocks x 576 (1/CU, 25 n
// each).  Rationale (round 6): kernel-internal optimizations moved total by
// ~±6us while arithmetic predicted ±40 — the ~100us gap between kernel-sum
// (~80us) and total (~187us) lives BETWEEN dispatches.  So: fewer
// dispatches.  Phase A embeds 25 baskets directly into LDS sq (identical
// gather/reduce arithmetic to the proven K1 -> bit-identical values; seq
// global round-trip deleted).  Phase B is round-6's matvec (proven correct)
// reading sq from LDS (its preload phase deleted).
// ---------------------------------------------------------------------------
__global__ __launch_bounds__(576) void embed_gi_kernel(
    const int* __restrict__ x,            // [N_][33]
    const float* __restrict__ encode_w,   // [100000][128]  (row 0 == 0)
    const float* __restrict__ wchange_w,  // [2][16]
    const float* __restrict__ w_ih,       // [432][144]
    const float* __restrict__ b_ih,       // [432]
    float* __restrict__ gi)               // [N_][432]
{
    int n0 = blockIdx.x * 25;
    int tid = threadIdx.x;

    __shared__ int xiAll[25 * 33];                  // 3.3 KB
    __shared__ __align__(16) float part[32 * 132];  // 16.9 KB (stride-132: proven 0-conflict)
    __shared__ float cntf[32];
    __shared__ __align__(16) float sq[25 * 160];    // 16 KB, k-padded rows

    // preload all 25 baskets' x; zero sq pad columns [144..160)
    for (int idx = tid; idx < 25 * 33; idx += 576)
        xiAll[idx] = x[(size_t)n0 * 33 + idx];
    for (int idx = tid; idx < 25 * 16; idx += 576) {
        int i = idx >> 4, c = idx & 15;
        sq[i * 160 + 144 + c] = 0.f;
    }
    __syncthreads();

    // ---- Phase A: embed, one basket at a time (2 barriers each) ----
    int it_i = tid >> 4;      // item 0..31 (tid<512)
    int it_j = tid & 15;      // col octet [8j, 8j+8)
    for (int i = 0; i < 25; ++i) {
        if (tid < 512) {
            int it = xiAll[i * 33 + it_i];
            const float* row = &encode_w[(size_t)it * E_];
            float4 v0 = *(const float4*)&row[8 * it_j + 0];
            float4 v1 = *(const float4*)&row[8 * it_j + 4];
            float* p = &part[it_i * 132 + 8 * it_j];
            *(float4*)&p[0] = v0;
            *(float4*)&p[4] = v1;
            if (it_j == 0) cntf[it_i] = (it != 0) ? 1.f : 0.f;
        }
        __syncthreads();
        if (tid < E_) {
            float s = 0.f, cn = 0.f;
            #pragma unroll
            for (int k = 0; k < 32; ++k) {
                s  += part[k * 132 + tid];   // same order as K1: bit-identical
                cn += cntf[k];
            }
            sq[i * 160 + tid] = s / fmaxf(cn, 1.f);
        } else if (tid < E_ + EW_) {
            int c = tid - E_;
            sq[i * 160 + E_ + c] = wchange_w[xiAll[i * 33 + 32] * EW_ + c];
        }
        __syncthreads();   // part reuse: reduce-reads before next gather-writes
    }

    // ---- Phase B: weights-stationary matvec (round-6 structure) ----
    int g = tid >> 3;         // 0..71 -> rows 6g..6g+5
    int s = tid & 7;          // k-chunk [20s, 20s+20)
    int k0 = s * 20;

    float w[6][20];
    #pragma unroll
    for (int r = 0; r < 6; ++r) {
        const float* wrow = &w_ih[(size_t)(6 * g + r) * D_];
        #pragma unroll
        for (int q = 0; q < 5; ++q) {
            int k = k0 + 4 * q;
            float4 t = make_float4(0.f, 0.f, 0.f, 0.f);
            if (k < D_) t = *(const float4*)&wrow[k];
            w[r][4 * q + 0] = t.x;
            w[r][4 * q + 1] = t.y;
            w[r][4 * q + 2] = t.z;
            w[r][4 * q + 3] = t.w;
        }
    }
    float bias = (s < 6) ? b_ih[6 * g + s] : 0.f;
    // sq complete (loop ended with __syncthreads); no extra barrier needed

    const float* hp = sq + k0;
    float* gp = gi + (size_t)n0 * G_ + 6 * g + s;
    for (int i = 0; i < 25; ++i) {
        float hv[20];
        #pragma unroll
        for (int q = 0; q < 5; ++q) {
            float4 t4 = *(const float4*)&hp[i * 160 + 4 * q];
            hv[4 * q + 0] = t4.x;
            hv[4 * q + 1] = t4.y;
            hv[4 * q + 2] = t4.z;
            hv[4 * q + 3] = t4.w;
        }
        float a0 = 0.f, a1 = 0.f, a2 = 0.f, a3 = 0.f, a4 = 0.f, a5 = 0.f;
        #pragma unroll
        for (int kk = 0; kk < 20; ++kk) {
            float hk = hv[kk];
            a0 = fmaf(w[0][kk], hk, a0);
            a1 = fmaf(w[1][kk], hk, a1);
            a2 = fmaf(w[2][kk], hk, a2);
            a3 = fmaf(w[3][kk], hk, a3);
            a4 = fmaf(w[4][kk], hk, a4);
            a5 = fmaf(w[5][kk], hk, a5);
        }
        DPP_RED3(a0); DPP_RED3(a1); DPP_RED3(a2);
        DPP_RED3(a3); DPP_RED3(a4); DPP_RED3(a5);
        float myacc = a0;
        if (s == 1) myacc = a1;
        if (s == 2) myacc = a2;
        if (s == 3) myacc = a3;
        if (s == 4) myacc = a4;
        if (s == 5) myacc = a5;
        if (s < 6) gp[(size_t)i * G_] = myacc + bias;
    }
}

// ---------------------------------------------------------------------------
// K34: GRU v6 (best measured) + fc TAIL.  Changes vs v6:
//  - per-step h_t goes to LDS hcache[50][160] (32KB) instead of the hseq
//    global store (hseq deleted entirely — only K4 consumed it).
//  - after the T-loop, w_hh's registers are dead; the tail reuses that
//    budget for fc rows {2g,2g+1} (g<64) and runs round-6's proven
//    fc-matvec over the cached rows.  No concurrent pressure with the main
//    loop (the round-2 spill disaster was CONCURRENT fc weights).
//  - hcache rows padded to 160 so the s=7 chunk [140,160) reads zeros,
//    matching the zero-padded weights.  Stride 160 = bank-aligned:
//    writes are 2 lanes/bank (free), tail b128 reads 8-way broadcast on
//    disjoint bank quads (conflict-free).
// ---------------------------------------------------------------------------
__global__ __launch_bounds__(576) void gru_fc_kernel(
    const float* __restrict__ gi,     // [N_][432]
    const float* __restrict__ w_hh,   // [432][144]
    const float* __restrict__ b_hh,   // [432]
    const float* __restrict__ h0,     // [128][144]
    const float* __restrict__ fc_w,   // [128][144]
    const float* __restrict__ fc_b,   // [128]
    float* __restrict__ dyn,          // [N_][128]
    float* __restrict__ hlast)        // [128][144]
{
    int b = blockIdx.x;
    int tid = threadIdx.x;
    int g = tid >> 3;       // 0..71  -> rows 6g..6g+5
    int s = tid & 7;        // k-chunk [20s, 20s+20)
    int k0 = s * 20;

    __shared__ __align__(16) float h[160];          // k-padded
    __shared__ float gh[G_];
    __shared__ __align__(16) float hcache[T_ * 160]; // 32 KB, k-padded rows

    float w[6][20];
    #pragma unroll
    for (int r = 0; r < 6; ++r) {
        const float* wrow = &w_hh[(size_t)(6 * g + r) * D_];
        #pragma unroll
        for (int q = 0; q < 5; ++q) {
            int k = k0 + 4 * q;
            float4 t = make_float4(0.f, 0.f, 0.f, 0.f);
            if (k < D_) t = *(const float4*)&wrow[k];
            w[r][4 * q + 0] = t.x;
            w[r][4 * q + 1] = t.y;
            w[r][4 * q + 2] = t.z;
            w[r][4 * q + 3] = t.w;
        }
    }
    float bias = (s < 6) ? b_hh[6 * g + s] : 0.f;

    if (tid < 160) h[tid] = (tid < D_) ? h0[b * D_ + tid] : 0.f;
    // zero hcache pad columns [144..160) once
    for (int idx = tid; idx < T_ * 16; idx += 576) {
        int i = idx >> 4, c = idx & 15;
        hcache[i * 160 + 144 + c] = 0.f;
    }
    __syncthreads();

    // gi pipeline: registers hold step t's values at top of iteration t
    float gir = 0.f, giz = 0.f, gin = 0.f;
    if (tid < D_) {
        const float* gp = &gi[(size_t)(b * T_) * G_];
        gir = gp[tid];
        giz = gp[D_ + tid];
        gin = gp[2 * D_ + tid];
    }

    for (int t = 0; t < T_; ++t) {
        int n = b * T_ + t;

        float girU = gir, gizU = giz, ginU = gin;
        if (tid < D_ && t + 1 < T_) {
            const float* gp = &gi[(size_t)(n + 1) * G_];
            gir = gp[tid];
            giz = gp[D_ + tid];
            gin = gp[2 * D_ + tid];
        }

        float hv[20];
        #pragma unroll
        for (int q = 0; q < 5; ++q) {
            float4 t4 = *(const float4*)&h[k0 + 4 * q];
            hv[4 * q + 0] = t4.x;
            hv[4 * q + 1] = t4.y;
            hv[4 * q + 2] = t4.z;
            hv[4 * q + 3] = t4.w;
        }

        float a0 = 0.f, a1 = 0.f, a2 = 0.f, a3 = 0.f, a4 = 0.f, a5 = 0.f;
        #pragma unroll
        for (int kk = 0; kk < 20; ++kk) {
            float hk = hv[kk];
            a0 = fmaf(w[0][kk], hk, a0);
            a1 = fmaf(w[1][kk], hk, a1);
            a2 = fmaf(w[2][kk], hk, a2);
            a3 = fmaf(w[3][kk], hk, a3);
            a4 = fmaf(w[4][kk], hk, a4);
            a5 = fmaf(w[5][kk], hk, a5);
        }

        DPP_RED3(a0); DPP_RED3(a1); DPP_RED3(a2);
        DPP_RED3(a3); DPP_RED3(a4); DPP_RED3(a5);

        float myacc = a0;
        if (s == 1) myacc = a1;
        if (s == 2) myacc = a2;
        if (s == 3) myacc = a3;
        if (s == 4) myacc = a4;
        if (s == 5) myacc = a5;
        if (s < 6) gh[6 * g + s] = myacc + bias;
        __syncthreads();

        if (tid < D_) {
            float r = 1.f / (1.f + __expf(-(girU + gh[tid])));
            float z = 1.f / (1.f + __expf(-(gizU + gh[D_ + tid])));
            float narg = ginU + r * gh[2 * D_ + tid];
            narg = fminf(fmaxf(narg, -15.f), 15.f);
            float e2 = __expf(-2.f * narg);
            float nn = (1.f - e2) / (1.f + e2);
            float hn = (1.f - z) * nn + z * h[tid];
            hcache[t * 160 + tid] = hn;    // LDS instead of global hseq
            h[tid] = hn;
        }
        __syncthreads();
    }

    if (tid < D_) hlast[b * D_ + tid] = h[tid];

    // ---- fc tail: dyn[n] = fc_w @ h_n + fc_b over the 50 cached rows ----
    if (g < 64) {
        float wf0[20], wf1[20];
        #pragma unroll
        for (int q = 0; q < 5; ++q) {
            int k = k0 + 4 * q;
            float4 t0 = make_float4(0.f, 0.f, 0.f, 0.f);
            float4 t1 = t0;
            if (k < D_) {
                t0 = *(const float4*)&fc_w[(size_t)(2 * g + 0) * D_ + k];
                t1 = *(const float4*)&fc_w[(size_t)(2 * g + 1) * D_ + k];
            }
            wf0[4 * q + 0] = t0.x; wf0[4 * q + 1] = t0.y;
            wf0[4 * q + 2] = t0.z; wf0[4 * q + 3] = t0.w;
            wf1[4 * q + 0] = t1.x; wf1[4 * q + 1] = t1.y;
            wf1[4 * q + 2] = t1.z; wf1[4 * q + 3] = t1.w;
        }
        float fb = (s < 2) ? fc_b[2 * g + s] : 0.f;

        const float* hp = hcache + k0;
        float* dp = dyn + (size_t)(b * T_) * E_ + 2 * g + s;
        for (int i = 0; i < T_; ++i) {
            float hv[20];
            #pragma unroll
            for (int q = 0; q < 5; ++q) {
                float4 t4 = *(const float4*)&hp[i * 160 + 4 * q];
                hv[4 * q + 0] = t4.x;
                hv[4 * q + 1] = t4.y;
                hv[4 * q + 2] = t4.z;
                hv[4 * q + 3] = t4.w;
            }
            float f0 = 0.f, f1 = 0.f;
            #pragma unroll
            for (int kk = 0; kk < 20; ++kk) {
                float hk = hv[kk];
                f0 = fmaf(wf0[kk], hk, f0);
                f1 = fmaf(wf1[kk], hk, f1);
            }
            DPP_RED3(f0); DPP_RED3(f1);
            if (s < 2) dp[(size_t)i * E_] = ((s == 0) ? f0 : f1) + fb;
        }
    }
}

// ---------------------------------------------------------------------------
extern "C" void kernel_launch(void* const* d_in, const int* in_sizes, int n_in,
                              void* d_out, int out_size, void* d_ws, size_t ws_size,
                              hipStream_t stream)
{
    const int*   x         = (const int*)d_in[0];
    // d_in[1] = lengths (unused by the reference computation)
    const float* hidden    = (const float*)d_in[2];
    const float* encode_w  = (const float*)d_in[3];
    const float* wchange_w = (const float*)d_in[4];
    const float* w_ih      = (const float*)d_in[5];
    const float* w_hh      = (const float*)d_in[6];
    const float* b_ih      = (const float*)d_in[7];
    const float* b_hh      = (const float*)d_in[8];
    const float* fc_w      = (const float*)d_in[9];
    const float* fc_b      = (const float*)d_in[10];

    float* out = (float*)d_out;              // [N_][128] then [128][144]
    float* gi  = (float*)d_ws;               // 2764800 floats (11 MB)

    // K12: embed + gi matvec (one persistent kernel; seq never leaves LDS)
    embed_gi_kernel<<<256, 576, 0, stream>>>(x, encode_w, wchange_w,
                                             w_ih, b_ih, gi);

    // K34: GRU + fc tail (hseq never leaves LDS)
    gru_fc_kernel<<<B_, 576, 0, stream>>>(gi, w_hh, b_hh, hidden,
                                          fc_w, fc_b,
                                          out, out + (size_t)N_ * E_);
}

// Round 8
// 182.923 us; speedup vs baseline: 1.1202x; 1.1202x over previous
//
#include <hip/hip_runtime.h>
#include <math.h>

#define B_   128
#define T_   50
#define MI_  32
#define E_   128
#define EW_  16
#define D_   144
#define G_   432        // 3*D
#define N_   (B_*T_)    // 6400

// ---------------------------------------------------------------------------
// K1: basket embedding v2 — parallel gather (r3 config, known good).
// ---------------------------------------------------------------------------
__global__ __launch_bounds__(256) void embed_kernel(
    const int* __restrict__ x,            // [N_][33]
    const float* __restrict__ encode_w,   // [100000][128]  (row 0 == 0)
    const float* __restrict__ wchange_w,  // [2][16]
    float* __restrict__ seq)              // [N_][144]
{
    int n = blockIdx.x;
    int tid = threadIdx.x;
    int i = tid >> 3;        // item 0..31
    int j = tid & 7;         // col chunk [16j, 16j+16)

    __shared__ int xi[33];
    __shared__ __align__(16) float part[32 * 132];  // stride 132 words
    __shared__ float cntf[32];

    if (tid < 33) xi[tid] = x[n * 33 + tid];
    __syncthreads();

    int it = xi[i];
    const float* row = &encode_w[(size_t)it * E_];
    float4 v0 = *(const float4*)&row[16 * j + 0];
    float4 v1 = *(const float4*)&row[16 * j + 4];
    float4 v2 = *(const float4*)&row[16 * j + 8];
    float4 v3 = *(const float4*)&row[16 * j + 12];

    float* p = &part[i * 132 + 16 * j];
    *(float4*)&p[0]  = v0;
    *(float4*)&p[4]  = v1;
    *(float4*)&p[8]  = v2;
    *(float4*)&p[12] = v3;
    if (j == 0) cntf[i] = (it != 0) ? 1.f : 0.f;
    __syncthreads();

    if (tid < E_) {
        int c = tid;
        float s = 0.f, cn = 0.f;
        #pragma unroll
        for (int k = 0; k < 32; ++k) {
            s  += part[k * 132 + c];   // 2-way bank aliasing: free
            cn += cntf[k];             // broadcast: free
        }
        seq[n * D_ + c] = s / fmaxf(cn, 1.f);
    } else if (tid < E_ + EW_) {
        int c = tid - E_;
        seq[n * D_ + E_ + c] = wchange_w[xi[32] * EW_ + c];
    }
}

// ---------------------------------------------------------------------------
// K2/K4: single-buffer 64x64 tiled GEMM (r3 config — best measured; the
// 128x128 tile, LDS dbuf, and persistent-matvec variants all regressed or
// were null in rounds 4-6).
// ---------------------------------------------------------------------------
#define GK   144
#define GBK  48
#define GPAD 68

__global__ __launch_bounds__(256) void gemm_bias_kernel(
    const float* __restrict__ A,
    const float* __restrict__ Bw,
    const float* __restrict__ bias,
    float* __restrict__ C,
    int M, int N)
{
    __shared__ float As[GBK * GPAD];
    __shared__ float Bs[GBK * GPAD];

    int tid = threadIdx.x;
    int row0 = blockIdx.x * 64;
    int col0 = blockIdx.y * 64;
    int tx = tid & 15;        // col group
    int ty = tid >> 4;        // row group

    float acc[4][4] = {};

    int sr = tid >> 2;
    int skq0 = tid & 3;

    for (int k0 = 0; k0 < GK; k0 += GBK) {
        __syncthreads();
        #pragma unroll
        for (int i = 0; i < 3; ++i) {
            int kq = skq0 + i * 4;          // 0..11  (48 k / 4)
            float4 a = *(const float4*)&A[(size_t)(row0 + sr) * GK + k0 + kq * 4];
            int nrow = col0 + sr;
            float4 b = make_float4(0.f, 0.f, 0.f, 0.f);
            if (nrow < N)
                b = *(const float4*)&Bw[(size_t)nrow * GK + k0 + kq * 4];
            As[(kq * 4 + 0) * GPAD + sr] = a.x;
            As[(kq * 4 + 1) * GPAD + sr] = a.y;
            As[(kq * 4 + 2) * GPAD + sr] = a.z;
            As[(kq * 4 + 3) * GPAD + sr] = a.w;
            Bs[(kq * 4 + 0) * GPAD + sr] = b.x;
            Bs[(kq * 4 + 1) * GPAD + sr] = b.y;
            Bs[(kq * 4 + 2) * GPAD + sr] = b.z;
            Bs[(kq * 4 + 3) * GPAD + sr] = b.w;
        }
        __syncthreads();

        #pragma unroll 4
        for (int k = 0; k < GBK; ++k) {
            float4 a4 = *(const float4*)&As[k * GPAD + ty * 4];
            float4 b4 = *(const float4*)&Bs[k * GPAD + tx * 4];
            float av[4] = {a4.x, a4.y, a4.z, a4.w};
            float bv[4] = {b4.x, b4.y, b4.z, b4.w};
            #pragma unroll
            for (int i = 0; i < 4; ++i)
                #pragma unroll
                for (int j = 0; j < 4; ++j)
                    acc[i][j] = fmaf(av[i], bv[j], acc[i][j]);
        }
    }

    int c = col0 + tx * 4;
    if (c < N) {
        float4 bb = *(const float4*)&bias[c];
        #pragma unroll
        for (int i = 0; i < 4; ++i) {
            int r = row0 + ty * 4 + i;
            float4 o;
            o.x = acc[i][0] + bb.x;
            o.y = acc[i][1] + bb.y;
            o.z = acc[i][2] + bb.z;
            o.w = acc[i][3] + bb.w;
            *(float4*)&C[(size_t)r * N + c] = o;
        }
    }
}

// ---------------------------------------------------------------------------
// K3: GRU v8 = v6 arithmetic with BALANCED 512 threads (8 waves = exactly
// 2/SIMD).  v6's 576 threads = 9 waves = {3,2,2,2}/SIMD: both per-step
// barriers sync to the 3-wave straggler SIMD (~990 vs ~660 cyc issue) —
// ~330 cyc/step wasted.  New mapping: 64 groups x 8 lanes; groups 0..47 own
// 7 rows (7g..7g+6), groups 48..63 own 6 rows (336+6(g-48)..) — covers 432.
// Row count is wave-uniform (8 same-size groups per wave).  Per-row
// arithmetic (20-k chunks, same DPP butterfly, bias after reduce) is
// BIT-IDENTICAL to v6 -> absmax unchanged.  __launch_bounds__(512,2):
// 2 waves/EU -> VGPR cap 256; w[7][20]+hv[20] ~ 175 regs, no spill
// (the v5 spill was 9 waves -> 170-reg cap).
// ---------------------------------------------------------------------------
template<int CTRL>
__device__ __forceinline__ float dpp_xor_add(float x) {
    int y = __builtin_amdgcn_mov_dpp(__float_as_int(x), CTRL, 0xF, 0xF, true);
    return x + __int_as_float(y);
}
#define DPP_RED3(v) \
    v = dpp_xor_add<0xB1>(v); v = dpp_xor_add<0x4E>(v); v = dpp_xor_add<0x141>(v);

__global__ __launch_bounds__(512, 2) void gru_kernel(
    const float* __restrict__ gi,     // [N_][432]
    const float* __restrict__ w_hh,   // [432][144]
    const float* __restrict__ b_hh,   // [432]
    const float* __restrict__ h0,     // [128][144]
    float* __restrict__ hseq,         // [N_][144]
    float* __restrict__ hlast)        // [128][144]
{
    int b = blockIdx.x;
    int tid = threadIdx.x;
    int g = tid >> 3;       // 0..63
    int s = tid & 7;        // k-chunk [20s, 20s+20)
    int k0 = s * 20;

    // row block: first 48 groups take 7 rows, last 16 take 6 (48*7+16*6=432)
    bool g7 = (g < 48);                       // wave-uniform
    int rb = g7 ? 7 * g : 336 + 6 * (g - 48); // base row
    int rc = g7 ? 7 : 6;                      // row count

    __shared__ __align__(16) float h[160];   // k-padded; [144..159] stay 0
    __shared__ float gh[G_];

    // weights into VGPRs (zero-padded past k=143; unused 7th row = zeros)
    float w[7][20];
    #pragma unroll
    for (int r = 0; r < 7; ++r) {
        #pragma unroll
        for (int q = 0; q < 5; ++q) {
            int k = k0 + 4 * q;
            float4 t = make_float4(0.f, 0.f, 0.f, 0.f);
            if (r < rc && k < D_)
                t = *(const float4*)&w_hh[(size_t)(rb + r) * D_ + k];
            w[r][4 * q + 0] = t.x;
            w[r][4 * q + 1] = t.y;
            w[r][4 * q + 2] = t.z;
            w[r][4 * q + 3] = t.w;
        }
    }
    float bias = (s < rc) ? b_hh[rb + s] : 0.f;

    if (tid < 160) h[tid] = (tid < D_) ? h0[b * D_ + tid] : 0.f;
    __syncthreads();

    // gi pipeline: registers hold step t's values at top of iteration t
    float gir = 0.f, giz = 0.f, gin = 0.f;
    if (tid < D_) {
        const float* gp = &gi[(size_t)(b * T_) * G_];
        gir = gp[tid];
        giz = gp[D_ + tid];
        gin = gp[2 * D_ + tid];
    }

    for (int t = 0; t < T_; ++t) {
        int n = b * T_ + t;

        float girU = gir, gizU = giz, ginU = gin;
        if (tid < D_ && t + 1 < T_) {
            const float* gp = &gi[(size_t)(n + 1) * G_];
            gir = gp[tid];
            giz = gp[D_ + tid];
            gin = gp[2 * D_ + tid];
        }

        // h chunk: 5 conflict-free ds_read_b128
        float hv[20];
        #pragma unroll
        for (int q = 0; q < 5; ++q) {
            float4 t4 = *(const float4*)&h[k0 + 4 * q];
            hv[4 * q + 0] = t4.x;
            hv[4 * q + 1] = t4.y;
            hv[4 * q + 2] = t4.z;
            hv[4 * q + 3] = t4.w;
        }

        // 6 (or 7) rows x 20 k partial dots; 7th chain wave-uniform branch
        float a0 = 0.f, a1 = 0.f, a2 = 0.f, a3 = 0.f, a4 = 0.f, a5 = 0.f;
        float a6 = 0.f;
        #pragma unroll
        for (int kk = 0; kk < 20; ++kk) {
            float hk = hv[kk];
            a0 = fmaf(w[0][kk], hk, a0);
            a1 = fmaf(w[1][kk], hk, a1);
            a2 = fmaf(w[2][kk], hk, a2);
            a3 = fmaf(w[3][kk], hk, a3);
            a4 = fmaf(w[4][kk], hk, a4);
            a5 = fmaf(w[5][kk], hk, a5);
        }
        if (g7) {
            #pragma unroll
            for (int kk = 0; kk < 20; ++kk)
                a6 = fmaf(w[6][kk], hv[kk], a6);
        }

        // reduce across the 8 k-chunk lanes: VALU DPP butterfly (no LDS)
        DPP_RED3(a0); DPP_RED3(a1); DPP_RED3(a2);
        DPP_RED3(a3); DPP_RED3(a4); DPP_RED3(a5);
        if (g7) { DPP_RED3(a6); }

        // lane s writes row rb+s (s<rc); all 8 lanes hold all sums
        float myacc = a0;
        if (s == 1) myacc = a1;
        if (s == 2) myacc = a2;
        if (s == 3) myacc = a3;
        if (s == 4) myacc = a4;
        if (s == 5) myacc = a5;
        if (s == 6) myacc = a6;
        if (s < rc) gh[rb + s] = myacc + bias;
        __syncthreads();

        if (tid < D_) {
            float r = 1.f / (1.f + __expf(-(girU + gh[tid])));
            float z = 1.f / (1.f + __expf(-(gizU + gh[D_ + tid])));
            float narg = ginU + r * gh[2 * D_ + tid];
            narg = fminf(fmaxf(narg, -15.f), 15.f);
            float e2 = __expf(-2.f * narg);
            float nn = (1.f - e2) / (1.f + e2);
            float hn = (1.f - z) * nn + z * h[tid];
            hseq[(size_t)n * D_ + tid] = hn;
            h[tid] = hn;
        }
        __syncthreads();
    }

    if (tid < D_) hlast[b * D_ + tid] = h[tid];
}

// ---------------------------------------------------------------------------
extern "C" void kernel_launch(void* const* d_in, const int* in_sizes, int n_in,
                              void* d_out, int out_size, void* d_ws, size_t ws_size,
                              hipStream_t stream)
{
    const int*   x         = (const int*)d_in[0];
    // d_in[1] = lengths (unused by the reference computation)
    const float* hidden    = (const float*)d_in[2];
    const float* encode_w  = (const float*)d_in[3];
    const float* wchange_w = (const float*)d_in[4];
    const float* w_ih      = (const float*)d_in[5];
    const float* w_hh      = (const float*)d_in[6];
    const float* b_ih      = (const float*)d_in[7];
    const float* b_hh      = (const float*)d_in[8];
    const float* fc_w      = (const float*)d_in[9];
    const float* fc_b      = (const float*)d_in[10];

    float* out = (float*)d_out;              // [N_][128] then [128][144]
    float* ws  = (float*)d_ws;
    float* seq  = ws;                        //   921600 floats
    float* gi   = ws + 921600;               //  2764800 floats
    float* hseq = ws + 921600 + 2764800;     //   921600 floats  (18.4 MB total)

    // K1: embedding (parallel gather v2)
    embed_kernel<<<N_, 256, 0, stream>>>(x, encode_w, wchange_w, seq);

    // K2: gi = seq @ w_ih^T + b_ih   (M=6400, N=432)
    gemm_bias_kernel<<<dim3(N_ / 64, (G_ + 63) / 64), 256, 0, stream>>>(
        seq, w_ih, b_ih, gi, N_, G_);

    // K3: GRU over T=50 (v8: balanced 512 threads, 2 waves/SIMD)
    gru_kernel<<<B_, 512, 0, stream>>>(gi, w_hh, b_hh, hidden, hseq,
                                       out + (size_t)N_ * E_);

    // K4: dynamic_user = hseq @ fc_w^T + fc_b   (M=6400, N=128)
    gemm_bias_kernel<<<dim3(N_ / 64, E_ / 64), 256, 0, stream>>>(
        hseq, fc_w, fc_b, out, N_, E_);
}